// Round 3
// baseline (111.059 us; speedup 1.0000x reference)
//
#include <hip/hip_runtime.h>
#include <hip/hip_cooperative_groups.h>

namespace cg = cooperative_groups;

#define ROWN 512
constexpr float MARGIN = 1.0f;
constexpr float NEG_INF = -1e30f;

// Single cooperative kernel: one block per row computes its partial hinge sum
// and pair count into d_ws; grid.sync(); block 0 reduces 512 partials (double)
// and writes the scalar. 512 blocks x 256 thr = 2 blocks/CU, co-resident.
__global__ __launch_bounds__(256) void pmrl_fused(const float* __restrict__ scores,
                                                  const int* __restrict__ labels,
                                                  float* __restrict__ row_sum,
                                                  unsigned int* __restrict__ row_pairs,
                                                  float* __restrict__ out) {
    __shared__ float pos_s[ROWN];
    __shared__ float neg_s[ROWN + 4];   // +4 for -inf padding to multiple of 4
    __shared__ int cnts[2];             // [0]=pos count, [1]=neg count
    __shared__ float wsum[4];

    const int row  = blockIdx.x;
    const int t    = threadIdx.x;
    const int lane = t & 63;

    if (t < 2) cnts[t] = 0;
    __syncthreads();

    const float* s = scores + (size_t)row * ROWN;
    const int*   l = labels + (size_t)row * ROWN;

    #pragma unroll
    for (int r = 0; r < 2; ++r) {
        const int i   = t + r * 256;
        const float v = s[i];
        const int lab = l[i];
        const bool isp = (lab == 1);
        const bool isn = (lab == 0);
        const unsigned long long bp = __ballot(isp);
        const unsigned long long bn = __ballot(isn);
        const unsigned long long ltmask = (1ull << lane) - 1ull;
        const int pp = __popcll(bp & ltmask);
        const int pn = __popcll(bn & ltmask);
        int basep = 0, basen = 0;
        if (lane == 0) {
            basep = atomicAdd(&cnts[0], __popcll(bp));
            basen = atomicAdd(&cnts[1], __popcll(bn));
        }
        basep = __shfl(basep, 0, 64);
        basen = __shfl(basen, 0, 64);
        if (isp) pos_s[basep + pp] = v;
        if (isn) neg_s[basen + pn] = v;
    }
    __syncthreads();

    const int P = cnts[0];
    const int Q = cnts[1];

    // pad negatives to a multiple of 4 with -inf so padded lanes contribute 0
    const int pad = (4 - (Q & 3)) & 3;
    if (t < pad) neg_s[Q + t] = NEG_INF;
    __syncthreads();
    const int Q4 = (Q + 3) >> 2;

    float acc = 0.0f;
    const float4* neg4 = (const float4*)neg_s;
    for (int i = t; i < P; i += 256) {
        const float c = MARGIN - pos_s[i];
        float a0 = 0.f, a1 = 0.f, a2 = 0.f, a3 = 0.f;
        for (int j = 0; j < Q4; ++j) {
            // same address across the wave -> ds_read_b128 broadcast, conflict-free
            const float4 n = neg4[j];
            a0 += fmaxf(c + n.x, 0.0f);
            a1 += fmaxf(c + n.y, 0.0f);
            a2 += fmaxf(c + n.z, 0.0f);
            a3 += fmaxf(c + n.w, 0.0f);
        }
        acc += (a0 + a1) + (a2 + a3);
    }

    // wave(64) shuffle reduction, then 4-wave combine
    #pragma unroll
    for (int off = 32; off > 0; off >>= 1) acc += __shfl_down(acc, off, 64);
    if (lane == 0) wsum[t >> 6] = acc;
    __syncthreads();

    if (t == 0) {
        row_sum[row]   = (wsum[0] + wsum[1]) + (wsum[2] + wsum[3]);
        row_pairs[row] = (unsigned int)(P * Q);
    }

    cg::this_grid().sync();

    // block 0: final reduction in double for the ~4e7-magnitude total
    if (row == 0) {
        __shared__ double dsum[4];
        __shared__ unsigned long long dcnt[4];
        double ds = 0.0;
        unsigned long long pc = 0ull;
        #pragma unroll
        for (int r = 0; r < 2; ++r) {
            const int i = t + r * 256;
            ds += (double)row_sum[i];
            pc += (unsigned long long)row_pairs[i];
        }
        #pragma unroll
        for (int off = 32; off > 0; off >>= 1) {
            ds += __shfl_down(ds, off, 64);
            pc += __shfl_down(pc, off, 64);
        }
        if (lane == 0) { dsum[t >> 6] = ds; dcnt[t >> 6] = pc; }
        __syncthreads();
        if (t == 0) {
            const double total = (dsum[0] + dsum[1]) + (dsum[2] + dsum[3]);
            const unsigned long long n = dcnt[0] + dcnt[1] + dcnt[2] + dcnt[3];
            out[0] = (n > 0ull) ? (float)(total / (double)n) : 0.0f;
        }
    }
}

extern "C" void kernel_launch(void* const* d_in, const int* in_sizes, int n_in,
                              void* d_out, int out_size, void* d_ws, size_t ws_size,
                              hipStream_t stream) {
    const float* scores = (const float*)d_in[0];
    const int*   labels = (const int*)d_in[1];
    float*       out    = (float*)d_out;

    float*        row_sum   = (float*)d_ws;
    unsigned int* row_pairs = (unsigned int*)((char*)d_ws + ROWN * sizeof(float));

    void* args[] = {(void*)&scores, (void*)&labels, (void*)&row_sum,
                    (void*)&row_pairs, (void*)&out};
    hipLaunchCooperativeKernel((void*)pmrl_fused, dim3(ROWN), dim3(256),
                               args, 0, stream);
}

// Round 4
// 78.754 us; speedup vs baseline: 1.4102x; 1.4102x over previous
//
#include <hip/hip_runtime.h>

#define ROWN 512
constexpr float MARGIN = 1.0f;
constexpr float NEG_INF = -1e30f;
#define POISON_U 0xAAAAAAAAu   // harness re-poisons d_ws to 0xAA bytes before EVERY call

// Single non-cooperative kernel, one block per row:
//  1) ballot-compact pos/neg scores into LDS
//  2) float4 LDS inner loop accumulates hinge over pos x neg
//  3) block partial -> device-scope f32/u32 atomicAdd into d_ws accumulators
//     (which start at the known poison pattern, corrected at the end)
//  4) last block by ticket (old == POISON_U + 511) reads accumulators
//     coherently and writes the scalar. No grid sync, no 2nd dispatch.
__global__ __launch_bounds__(256) void pmrl_onepass(const float* __restrict__ scores,
                                                    const int* __restrict__ labels,
                                                    float* __restrict__ gsum,
                                                    unsigned int* __restrict__ gpairs,
                                                    unsigned int* __restrict__ ticket,
                                                    float* __restrict__ out) {
    __shared__ float pos_s[ROWN];
    __shared__ float neg_s[ROWN + 4];   // +4 for -inf padding to multiple of 4
    __shared__ int cnts[2];             // [0]=pos count, [1]=neg count
    __shared__ float wsum[4];

    const int row  = blockIdx.x;
    const int t    = threadIdx.x;
    const int lane = t & 63;

    if (t < 2) cnts[t] = 0;
    __syncthreads();

    const float* s = scores + (size_t)row * ROWN;
    const int*   l = labels + (size_t)row * ROWN;

    // 8B/lane vectorized stage; compaction order is irrelevant to the sum,
    // so processing (2t, 2t+1) per thread is fine.
    const float2 v2 = ((const float2*)s)[t];
    const int2   l2 = ((const int2*)l)[t];
    const float vv[2] = {v2.x, v2.y};
    const int   ll[2] = {l2.x, l2.y};

    #pragma unroll
    for (int r = 0; r < 2; ++r) {
        const float v  = vv[r];
        const int  lab = ll[r];
        const bool isp = (lab == 1);
        const bool isn = (lab == 0);
        const unsigned long long bp = __ballot(isp);
        const unsigned long long bn = __ballot(isn);
        const unsigned long long ltmask = (1ull << lane) - 1ull;
        const int pp = __popcll(bp & ltmask);
        const int pn = __popcll(bn & ltmask);
        int basep = 0, basen = 0;
        if (lane == 0) {
            basep = atomicAdd(&cnts[0], __popcll(bp));
            basen = atomicAdd(&cnts[1], __popcll(bn));
        }
        basep = __shfl(basep, 0, 64);
        basen = __shfl(basen, 0, 64);
        if (isp) pos_s[basep + pp] = v;
        if (isn) neg_s[basen + pn] = v;
    }
    __syncthreads();

    const int P = cnts[0];
    const int Q = cnts[1];

    // pad negatives to a multiple of 4 with -inf so padded lanes contribute 0
    const int pad = (4 - (Q & 3)) & 3;
    if (t < pad) neg_s[Q + t] = NEG_INF;
    __syncthreads();
    const int Q4 = (Q + 3) >> 2;

    float acc = 0.0f;
    const float4* neg4 = (const float4*)neg_s;
    for (int i = t; i < P; i += 256) {
        const float c = MARGIN - pos_s[i];
        float a0 = 0.f, a1 = 0.f, a2 = 0.f, a3 = 0.f;
        for (int j = 0; j < Q4; ++j) {
            // same address across the wave -> ds_read_b128 broadcast, conflict-free
            const float4 n = neg4[j];
            a0 += fmaxf(c + n.x, 0.0f);
            a1 += fmaxf(c + n.y, 0.0f);
            a2 += fmaxf(c + n.z, 0.0f);
            a3 += fmaxf(c + n.w, 0.0f);
        }
        acc += (a0 + a1) + (a2 + a3);
    }

    // wave(64) shuffle reduction, then 4-wave combine
    #pragma unroll
    for (int off = 32; off > 0; off >>= 1) acc += __shfl_down(acc, off, 64);
    if (lane == 0) wsum[t >> 6] = acc;
    __syncthreads();

    if (t == 0) {
        const float blocksum = (wsum[0] + wsum[1]) + (wsum[2] + wsum[3]);
        // device-scope accumulation; gsum starts at f32(0xAAAAAAAA) = -3.0e-13
        // (absorbed), gpairs starts at POISON_U (subtracted by the winner).
        atomicAdd(gsum, blocksum);
        atomicAdd(gpairs, (unsigned int)(P * Q));
        __threadfence();
        const unsigned int old = atomicAdd(ticket, 1u);
        if (old == POISON_U + (unsigned int)(ROWN - 1)) {
            __threadfence();
            // coherent read-back via atomic RMW with identity
            const float        total = atomicAdd(gsum, 0.0f);
            const unsigned int rawnp = atomicAdd(gpairs, 0u);
            const unsigned int np    = rawnp - POISON_U;  // exact integer count
            out[0] = (np > 0u) ? (total / (float)np) : 0.0f;
        }
    }
}

extern "C" void kernel_launch(void* const* d_in, const int* in_sizes, int n_in,
                              void* d_out, int out_size, void* d_ws, size_t ws_size,
                              hipStream_t stream) {
    const float* scores = (const float*)d_in[0];
    const int*   labels = (const int*)d_in[1];
    float*       out    = (float*)d_out;

    float*        gsum   = (float*)d_ws;
    unsigned int* gpairs = (unsigned int*)((char*)d_ws + 4);
    unsigned int* ticket = (unsigned int*)((char*)d_ws + 8);

    pmrl_onepass<<<ROWN, 256, 0, stream>>>(scores, labels, gsum, gpairs, ticket, out);
}

// Round 5
// 77.347 us; speedup vs baseline: 1.4359x; 1.0182x over previous
//
#include <hip/hip_runtime.h>

#define ROWN 512
#define RPB 4                      // rows per block (4 x 256-thread row-groups)
#define NBLK (ROWN / RPB)          // 128 blocks
constexpr float MARGIN = 1.0f;
constexpr float NEG_INF = -1e30f;
#define POISON_U 0xAAAAAAAAu       // harness poisons d_ws to 0xAA bytes before EVERY call

// One kernel. Each block handles 4 rows via independent 256-thread row-groups:
// ballot-compact pos/neg into LDS, float4 hinge loop, per-group reduce.
// Block partial -> distinct-address agent-scope store (no contention, no fence);
// last block by 128-op ticket (release sequence on the ticket RMW provides
// ordering) reduces 128 partials in double and writes the scalar.
__global__ __launch_bounds__(1024) void pmrl_onepass(const float* __restrict__ scores,
                                                     const int* __restrict__ labels,
                                                     float* __restrict__ psum,
                                                     unsigned int* __restrict__ pcnt,
                                                     unsigned int* __restrict__ ticket,
                                                     float* __restrict__ out) {
    __shared__ float pos_s[RPB][ROWN];
    __shared__ float neg_s[RPB][ROWN + 4];
    __shared__ int   cnts[RPB][2];
    __shared__ float wsum[RPB][4];
    __shared__ float gsum[RPB];
    __shared__ unsigned int gcnt[RPB];

    const int t    = threadIdx.x;
    const int g    = t >> 8;        // row-group 0..3
    const int t2   = t & 255;       // thread index within group
    const int lane = t & 63;
    const int row  = blockIdx.x * RPB + g;

    if (t2 < 2) cnts[g][t2] = 0;
    __syncthreads();

    const float* s = scores + (size_t)row * ROWN;
    const int*   l = labels + (size_t)row * ROWN;

    // 8B/lane stage; compaction order is irrelevant to the sum.
    const float2 v2 = ((const float2*)s)[t2];
    const int2   i2 = ((const int2*)l)[t2];
    const float vv[2] = {v2.x, v2.y};
    const int   ll[2] = {i2.x, i2.y};

    #pragma unroll
    for (int r = 0; r < 2; ++r) {
        const float v  = vv[r];
        const int  lab = ll[r];
        const bool isp = (lab == 1);
        const bool isn = (lab == 0);
        const unsigned long long bp = __ballot(isp);
        const unsigned long long bn = __ballot(isn);
        const unsigned long long ltmask = (1ull << lane) - 1ull;
        const int pp = __popcll(bp & ltmask);
        const int pn = __popcll(bn & ltmask);
        int basep = 0, basen = 0;
        if (lane == 0) {
            basep = atomicAdd(&cnts[g][0], __popcll(bp));
            basen = atomicAdd(&cnts[g][1], __popcll(bn));
        }
        basep = __shfl(basep, 0, 64);
        basen = __shfl(basen, 0, 64);
        if (isp) pos_s[g][basep + pp] = v;
        if (isn) neg_s[g][basen + pn] = v;
    }
    __syncthreads();

    const int P = cnts[g][0];
    const int Q = cnts[g][1];

    // pad negatives to a multiple of 4 with -inf so padded lanes contribute 0
    const int pad = (4 - (Q & 3)) & 3;
    if (t2 < pad) neg_s[g][Q + t2] = NEG_INF;
    __syncthreads();
    const int Q4 = (Q + 3) >> 2;

    float acc = 0.0f;
    const float4* neg4 = (const float4*)&neg_s[g][0];
    for (int i = t2; i < P; i += 256) {
        const float c = MARGIN - pos_s[g][i];
        float a0 = 0.f, a1 = 0.f, a2 = 0.f, a3 = 0.f;
        for (int j = 0; j < Q4; ++j) {
            // wave-uniform address -> ds_read_b128 broadcast, conflict-free
            const float4 n = neg4[j];
            a0 += fmaxf(c + n.x, 0.0f);
            a1 += fmaxf(c + n.y, 0.0f);
            a2 += fmaxf(c + n.z, 0.0f);
            a3 += fmaxf(c + n.w, 0.0f);
        }
        acc += (a0 + a1) + (a2 + a3);
    }

    // wave(64) shuffle reduction, then 4-wave combine per row-group
    #pragma unroll
    for (int off = 32; off > 0; off >>= 1) acc += __shfl_down(acc, off, 64);
    if (lane == 0) wsum[g][t2 >> 6] = acc;
    __syncthreads();

    if (t2 == 0) {
        gsum[g] = (wsum[g][0] + wsum[g][1]) + (wsum[g][2] + wsum[g][3]);
        gcnt[g] = (unsigned int)(P * Q);
    }
    __syncthreads();

    if (t == 0) {
        const float        bs = (gsum[0] + gsum[1]) + (gsum[2] + gsum[3]);
        const unsigned int bc = gcnt[0] + gcnt[1] + gcnt[2] + gcnt[3];
        // distinct addresses: parallel, uncontended, coherent (agent scope)
        __hip_atomic_store(&psum[blockIdx.x], bs, __ATOMIC_RELAXED, __HIP_MEMORY_SCOPE_AGENT);
        __hip_atomic_store(&pcnt[blockIdx.x], bc, __ATOMIC_RELAXED, __HIP_MEMORY_SCOPE_AGENT);
        // 128-op contended stream; acq_rel release-sequence orders the stores
        const unsigned int old = __hip_atomic_fetch_add(ticket, 1u, __ATOMIC_ACQ_REL,
                                                        __HIP_MEMORY_SCOPE_AGENT);
        if (old == POISON_U + (unsigned int)(NBLK - 1)) {
            double ds = 0.0;
            unsigned long long np = 0ull;
            #pragma unroll 8
            for (int i = 0; i < NBLK; ++i) {
                ds += (double)__hip_atomic_load(&psum[i], __ATOMIC_RELAXED,
                                                __HIP_MEMORY_SCOPE_AGENT);
                np += (unsigned long long)__hip_atomic_load(&pcnt[i], __ATOMIC_RELAXED,
                                                            __HIP_MEMORY_SCOPE_AGENT);
            }
            out[0] = (np > 0ull) ? (float)(ds / (double)np) : 0.0f;
        }
    }
}

extern "C" void kernel_launch(void* const* d_in, const int* in_sizes, int n_in,
                              void* d_out, int out_size, void* d_ws, size_t ws_size,
                              hipStream_t stream) {
    const float* scores = (const float*)d_in[0];
    const int*   labels = (const int*)d_in[1];
    float*       out    = (float*)d_out;

    // layout: ticket at 0 (own cacheline), partial sums at 256, counts after
    unsigned int* ticket = (unsigned int*)d_ws;
    float*        psum   = (float*)((char*)d_ws + 256);
    unsigned int* pcnt   = (unsigned int*)((char*)d_ws + 256 + NBLK * sizeof(float));

    pmrl_onepass<<<NBLK, 1024, 0, stream>>>(scores, labels, psum, pcnt, ticket, out);
}

// Round 6
// 62.425 us; speedup vs baseline: 1.7791x; 1.2390x over previous
//
#include <hip/hip_runtime.h>

#define ROWN 512
constexpr float MARGIN = 1.0f;
constexpr float NEG_INF = -1e30f;

// R5 = R1 structure (best: 64.2 us; fused variants all regressed 13-47 us due
// to contended device-scope atomics / grid-sync cost) + small safe wins:
// float2 staging, 2x-unrolled float4 inner loop, 256-thread final kernel.
__global__ __launch_bounds__(256) void pmrl_rows(const float* __restrict__ scores,
                                                 const int* __restrict__ labels,
                                                 float* __restrict__ row_sum,
                                                 unsigned int* __restrict__ row_pairs) {
    __shared__ float pos_s[ROWN];
    __shared__ float neg_s[ROWN + 8];   // pad to multiple of 8 with -inf
    __shared__ int cnts[2];             // [0]=pos count, [1]=neg count
    __shared__ float wsum[4];

    const int row  = blockIdx.x;
    const int t    = threadIdx.x;
    const int lane = t & 63;

    if (t < 2) cnts[t] = 0;
    __syncthreads();

    const float* s = scores + (size_t)row * ROWN;
    const int*   l = labels + (size_t)row * ROWN;

    // 8B/lane vectorized stage; compaction order is irrelevant to the sum.
    const float2 v2 = ((const float2*)s)[t];
    const int2   i2 = ((const int2*)l)[t];
    const float vv[2] = {v2.x, v2.y};
    const int   ll[2] = {i2.x, i2.y};

    #pragma unroll
    for (int r = 0; r < 2; ++r) {
        const float v  = vv[r];
        const int  lab = ll[r];
        const bool isp = (lab == 1);
        const bool isn = (lab == 0);
        const unsigned long long bp = __ballot(isp);
        const unsigned long long bn = __ballot(isn);
        const unsigned long long ltmask = (1ull << lane) - 1ull;
        const int pp = __popcll(bp & ltmask);
        const int pn = __popcll(bn & ltmask);
        int basep = 0, basen = 0;
        if (lane == 0) {
            basep = atomicAdd(&cnts[0], __popcll(bp));
            basen = atomicAdd(&cnts[1], __popcll(bn));
        }
        basep = __shfl(basep, 0, 64);
        basen = __shfl(basen, 0, 64);
        if (isp) pos_s[basep + pp] = v;
        if (isn) neg_s[basen + pn] = v;
    }
    __syncthreads();

    const int P = cnts[0];
    const int Q = cnts[1];

    // pad negatives to a multiple of 8 with -inf so padded lanes contribute 0
    const int pad = (8 - (Q & 7)) & 7;
    if (t < pad) neg_s[Q + t] = NEG_INF;
    __syncthreads();
    const int Q8 = (Q + 7) >> 3;

    float acc = 0.0f;
    const float4* neg4 = (const float4*)neg_s;
    for (int i = t; i < P; i += 256) {
        const float c = MARGIN - pos_s[i];
        float a0 = 0.f, a1 = 0.f, a2 = 0.f, a3 = 0.f;
        for (int j = 0; j < Q8; ++j) {
            // wave-uniform addresses -> ds_read_b128 broadcast, conflict-free
            const float4 n0 = neg4[2 * j];
            const float4 n1 = neg4[2 * j + 1];
            a0 += fmaxf(c + n0.x, 0.0f);
            a1 += fmaxf(c + n0.y, 0.0f);
            a2 += fmaxf(c + n0.z, 0.0f);
            a3 += fmaxf(c + n0.w, 0.0f);
            a0 += fmaxf(c + n1.x, 0.0f);
            a1 += fmaxf(c + n1.y, 0.0f);
            a2 += fmaxf(c + n1.z, 0.0f);
            a3 += fmaxf(c + n1.w, 0.0f);
        }
        acc += (a0 + a1) + (a2 + a3);
    }

    // wave(64) shuffle reduction, then 4-wave combine
    #pragma unroll
    for (int off = 32; off > 0; off >>= 1) acc += __shfl_down(acc, off, 64);
    if (lane == 0) wsum[t >> 6] = acc;
    __syncthreads();

    if (t == 0) {
        row_sum[row]   = (wsum[0] + wsum[1]) + (wsum[2] + wsum[3]);
        row_pairs[row] = (unsigned int)(P * Q);
    }
}

// One 256-thread block: each thread loads 2 partials, reduce in double.
__global__ __launch_bounds__(256) void pmrl_final(const float* __restrict__ row_sum,
                                                  const unsigned int* __restrict__ row_pairs,
                                                  float* __restrict__ out) {
    __shared__ double dsum[4];
    __shared__ unsigned long long dcnt[4];

    const int t    = threadIdx.x;
    const int lane = t & 63;

    double s = (double)row_sum[t] + (double)row_sum[t + 256];
    unsigned long long pc = (unsigned long long)row_pairs[t]
                          + (unsigned long long)row_pairs[t + 256];
    #pragma unroll
    for (int off = 32; off > 0; off >>= 1) {
        s  += __shfl_down(s, off, 64);
        pc += __shfl_down(pc, off, 64);
    }
    if (lane == 0) { dsum[t >> 6] = s; dcnt[t >> 6] = pc; }
    __syncthreads();
    if (t == 0) {
        const double total = (dsum[0] + dsum[1]) + (dsum[2] + dsum[3]);
        const unsigned long long n = dcnt[0] + dcnt[1] + dcnt[2] + dcnt[3];
        out[0] = (n > 0ull) ? (float)(total / (double)n) : 0.0f;
    }
}

extern "C" void kernel_launch(void* const* d_in, const int* in_sizes, int n_in,
                              void* d_out, int out_size, void* d_ws, size_t ws_size,
                              hipStream_t stream) {
    const float* scores = (const float*)d_in[0];
    const int*   labels = (const int*)d_in[1];
    float*       out    = (float*)d_out;

    float*        row_sum   = (float*)d_ws;
    unsigned int* row_pairs = (unsigned int*)((char*)d_ws + ROWN * sizeof(float));

    pmrl_rows<<<ROWN, 256, 0, stream>>>(scores, labels, row_sum, row_pairs);
    pmrl_final<<<1, 256, 0, stream>>>(row_sum, row_pairs, out);
}